// Round 14
// baseline (62.734 us; speedup 1.0000x reference)
//
#include <hip/hip_runtime.h>
#include <hip/hip_bf16.h>

// Problem constants
#define B_    2
#define T_    2
#define H_    56
#define W_    56
#define C_    256
#define NWW_  14             // windows along W (W_sp=4)
#define WC_   (W_ * C_)      // 14336
#define P1_   (H_ * W_ * C_) // 802816 (one (b,t) plane)
#define NWIN_ 448            // tokens per window
#define NPOOL_ 128           // pooled slots (112 real + 16 zero)
#define PMSZ_ 57344          // one pool-partial stripe: B*T*4*NWW*C
#define VIRT_ 320.0f         // zero-logit tokens folded analytically (896-576)
#define MEXP_ 16.0f          // fixed softmax max (exp2 domain)

typedef __bf16 bf16;
typedef __bf16 bf16x8 __attribute__((ext_vector_type(8)));
typedef float  f32x4  __attribute__((ext_vector_type(4)));
typedef short  s16x4  __attribute__((ext_vector_type(4)));
typedef short  s16x8  __attribute__((ext_vector_type(8)));
typedef unsigned int  uint;
typedef uint   uint4v __attribute__((ext_vector_type(4)));
typedef uint   uint2v __attribute__((ext_vector_type(2)));
typedef unsigned short u16;

__device__ __forceinline__ uint pack2(float a, float b) {
    u16 ha = __builtin_bit_cast(u16, (bf16)a);
    u16 hb = __builtin_bit_cast(u16, (bf16)b);
    return (uint)ha | ((uint)hb << 16);
}
__device__ __forceinline__ s16x4 pack4(float a, float b, float c, float d) {
    const uint2v u = {pack2(a, b), pack2(c, d)};
    return __builtin_bit_cast(s16x4, u);
}

// ---------------------------------------------------------------------------
// Pre-kernel: grid 392 x 256. One block = one 32-token chunk (b,t,ww,rc).
// Does: LePE conv -> d_out (f32) + K relayout + V transpose (LDS) + pool
// PARTIAL stripes (k,v read once; plain coalesced stores, no atomics).
// ---------------------------------------------------------------------------
__launch_bounds__(256, 4)
__global__ void pre_kernel(const float* __restrict__ k_in, const float* __restrict__ v_in,
                           const float* __restrict__ pool_w,
                           const float* __restrict__ gw, const float* __restrict__ gb,
                           bf16* __restrict__ kw, bf16* __restrict__ vw,
                           float* __restrict__ lep_out,
                           float* __restrict__ pmk_part, float* __restrict__ pmv_part) {
    __shared__ float pws[4][224];
    __shared__ u16  tileT[256 * 33];   // [c][tok] V transpose bounce

    const int bid = blockIdx.x;        // 0..391 = (b,t,ww,rc)
    const int tid = threadIdx.x;
    const int rc = bid % 7;
    const int ww = (bid / 7) % NWW_;
    const int t  = (bid / 98) % T_;
    const int b  = bid / 196;
    const int c  = tid;
    const int nh = c >> 5, hd = c & 31;
    const size_t bt = (size_t)(b * T_ + t) * P1_;
    const size_t winbase = ((size_t)((b * 8 + nh) * NWW_ + ww)) * NWIN_ * 32;

    for (int i = tid; i < 896; i += 256) pws[i / 224][i % 224] = pool_w[i];
    __syncthreads();

    float wv9[9];
    #pragma unroll
    for (int k = 0; k < 9; ++k) wv9[k] = gw[c * 9 + k];
    const float bias = gb[c];

    float pk[4] = {0.f, 0.f, 0.f, 0.f};
    float pv[4] = {0.f, 0.f, 0.f, 0.f};

    for (int hs = 0; hs < 4; ++hs) {
        // v rows rc*8 + hs*2 - 1 .. + 2
        float tile[4][4];
        #pragma unroll
        for (int dy = 0; dy < 4; ++dy) {
            const int hh = rc * 8 + hs * 2 - 1 + dy;
            const bool ok = (hh >= 0 && hh < H_);
            #pragma unroll
            for (int x = 0; x < 4; ++x)
                tile[dy][x] = ok ? v_in[bt + hh * WC_ + (ww * 4 + x) * C_ + c] : 0.f;
        }
        #pragma unroll
        for (int e = 0; e < 2; ++e) {
            const int h = rc * 8 + hs * 2 + e;
            #pragma unroll
            for (int wi = 0; wi < 4; ++wi) {
                const int tokc = hs * 8 + e * 4 + wi;   // 0..31 in chunk
                const int tokw = t * 224 + h * 4 + wi;  // token in window
                // LePE conv -> out (f32, image layout; full overwrite)
                float acc = bias;
                #pragma unroll
                for (int dy = 0; dy < 3; ++dy) {
                    #pragma unroll
                    for (int dx = -1; dx <= 1; ++dx) {
                        const int xx = wi + dx;
                        if (xx >= 0 && xx < 4)
                            acc += wv9[dy * 3 + dx + 1] * tile[e + dy][xx];
                    }
                }
                lep_out[bt + h * WC_ + (ww * 4 + wi) * C_ + c] = acc;
                // K relayout + pool partials
                const float kv = k_in[bt + h * WC_ + (ww * 4 + wi) * C_ + c];
                kw[winbase + (size_t)tokw * 32 + hd] = (bf16)kv;
                const float vv = tile[1 + e][wi];
                const int n = h * 4 + wi;               // pool index 0..223
                #pragma unroll
                for (int s = 0; s < 4; ++s) {
                    pk[s] += kv * pws[s][n];
                    pv[s] += vv * pws[s][n];
                }
                tileT[c * 33 + tokc] = __builtin_bit_cast(u16, (bf16)vv);
            }
        }
    }

    // pool partial stripe (plain coalesced stores)
    #pragma unroll
    for (int s = 0; s < 4; ++s) {
        const size_t o = (size_t)rc * PMSZ_ +
                         ((size_t)(((b * T_ + t) * 4 + s) * NWW_ + ww)) * C_ + c;
        pmk_part[o] = pk[s];
        pmv_part[o] = pv[s];
    }

    __syncthreads();

    // vw writeout: chunk ch = t*7+rc ; [b,nh,ww][ch][hd][slot]
    const int ch = t * 7 + rc;
    #pragma unroll
    for (int rep = 0; rep < 16; ++rep) {
        const int u  = tid + rep * 256;       // 0..4095 uints
        const int cc = u >> 4;
        const int p  = u & 15;
        const int tok0 = ((p >> 1) & 1) * 16 + (p >> 2) * 4 + ((2 * p) & 3);
        const uint val = (uint)tileT[cc * 33 + tok0] |
                         ((uint)tileT[cc * 33 + tok0 + 1] << 16);
        const size_t dst = (((size_t)((b * 8 + (cc >> 5)) * NWW_ + ww)) * 14 + ch) * 1024
                         + (cc & 31) * 32;
        ((uint*)vw)[dst / 2 + p] = val;
    }
}

// ---------------------------------------------------------------------------
// Finalize: sum the 7 pool stripes -> kp/vp (bf16, MFMA layouts) + zero pads.
// grid = 16 (bn), 256 threads.
// ---------------------------------------------------------------------------
__global__ void finalize_kernel(const float* __restrict__ pmk_part,
                                const float* __restrict__ pmv_part,
                                const float* __restrict__ pool_b,
                                bf16* __restrict__ kp, bf16* __restrict__ vp) {
    const int bn = blockIdx.x;
    const int b  = bn >> 3, nh = bn & 7;
    const int tid = threadIdx.x;
    const int hd = tid & 31;
    const int c  = nh * 32 + hd;

    for (int n = tid >> 5; n < 112; n += 8) {
        const int t = n / 56, r = n % 56;
        const int s = r / 14, j = r % 14;
        const size_t base = ((size_t)(((b * T_ + t) * 4 + s) * NWW_ + j)) * C_ + c;
        float sk = pool_b[s], sv = pool_b[s];
        #pragma unroll
        for (int rc = 0; rc < 7; ++rc) {
            sk += pmk_part[(size_t)rc * PMSZ_ + base];
            sv += pmv_part[(size_t)rc * PMSZ_ + base];
        }
        kp[((size_t)bn * NPOOL_ + n) * 32 + hd] = (bf16)sk;
        const int i5 = n & 31;
        const int slot = ((i5 & 15) >> 2) * 8 + (i5 >> 4) * 4 + (i5 & 3);
        vp[(((size_t)bn * 4 + (n >> 5)) * 32 + hd) * 32 + slot] = (bf16)sv;
    }
    // zero pads: kp tokens 112..127
    for (int z = tid; z < 512; z += 256)
        kp[((size_t)bn * NPOOL_ + 112) * 32 + z] = (bf16)0.f;
    // vp chunk 3, hi-half slots (gg*8+4..7)
    for (int z = tid; z < 512; z += 256) {
        const int hd2 = z >> 4, idx = z & 15;
        vp[(((size_t)bn * 4 + 3) * 32 + hd2) * 32 + ((idx >> 2) * 8 + 4 + (idx & 3))] = (bf16)0.f;
    }
}

// ---------------------------------------------------------------------------
// Streaming attention: 448-thr blocks (7 waves), 2 q-tiles/wave, fully
// unrolled chunk loops (static bases -> deep load pipelining at <=128 VGPR).
// All inner loads wave-contiguous b128. LePE read-modify-write on d_out.
// Bijective XCD swizzle. grid = 448.
// ---------------------------------------------------------------------------
__launch_bounds__(448, 4)
__global__ void attn_kernel(const float* __restrict__ q_in, const bf16* __restrict__ kw,
                            const bf16* __restrict__ vw, const bf16* __restrict__ kp,
                            const bf16* __restrict__ vp, float* __restrict__ out) {
    const int tid  = threadIdx.x;
    const int lane = tid & 63;
    const int wv   = tid >> 6;          // 0..6
    const int phys = blockIdx.x;        // 0..447 ; XCD = phys & 7
    const int xcd  = phys & 7;
    const int sl   = phys >> 3;         // 0..55
    const int hw   = xcd * 28 + (sl >> 1);  // (window,head) group 0..223
    const int half = sl & 1;
    const int nh   = hw & 7;
    const int nwi  = hw >> 3;
    const int b    = nwi / NWW_;
    const int ww   = nwi % NWW_;
    const int l15  = lane & 15;
    const int g    = lane >> 4;
    const int bn   = b * 8 + nh;
    const int cbase = nh * 32;
    const int tbase = half * 14 + wv;   // tiles tbase, tbase+7
    const float QS = 0.17677669529663687f * 1.4426950408889634f; // HD^-0.5 * log2(e)

    // ---- Q fragments (2 tiles), scaled into exp2 domain ----
    bf16x8 qf[2];
    #pragma unroll
    for (int ti = 0; ti < 2; ++ti) {
        const int qrow = (tbase + ti * 7) * 16 + l15;
        const int t = qrow / 224, r = qrow % 224;
        const int h = r >> 2, wi = r & 3;
        const size_t off = (size_t)(b * T_ + t) * P1_ + h * WC_ + (ww * 4 + wi) * C_ + cbase + g * 8;
        const f32x4 a0 = *(const f32x4*)(q_in + off);
        const f32x4 a1 = *(const f32x4*)(q_in + off + 4);
        const uint4v qp = {pack2(a0[0] * QS, a0[1] * QS), pack2(a0[2] * QS, a0[3] * QS),
                           pack2(a1[0] * QS, a1[1] * QS), pack2(a1[2] * QS, a1[3] * QS)};
        qf[ti] = __builtin_bit_cast(bf16x8, qp);
    }

    f32x4 o[2][2];
    float ssum[2];
    const f32x4 zf = {0.f, 0.f, 0.f, 0.f};
    #pragma unroll
    for (int ti = 0; ti < 2; ++ti) { o[ti][0] = zf; o[ti][1] = zf; ssum[ti] = 0.f; }

    const bf16* kwb = kw + ((size_t)(bn * NWW_ + ww)) * NWIN_ * 32;
    const bf16* vwb = vw + ((size_t)(bn * NWW_ + ww)) * 14 * 1024;
    const bf16* kpb = kp + (size_t)bn * NPOOL_ * 32;
    const bf16* vpb = vp + (size_t)bn * 4 * 1024;
    const int ko  = l15 * 32 + g * 8;
    const int ko2 = (16 + l15) * 32 + g * 8;

    auto compute = [&](const bf16* kc, const bf16* vc) {
        const bf16x8 ka = *(const bf16x8*)(kc + ko);
        const bf16x8 kb = *(const bf16x8*)(kc + ko2);
        const s16x8 va = __builtin_bit_cast(s16x8, *(const bf16x8*)(vc + ko));
        const s16x8 vb = __builtin_bit_cast(s16x8, *(const bf16x8*)(vc + ko2));
        const s16x4 v00 = {va[0], va[1], va[2], va[3]};
        const s16x4 v01 = {va[4], va[5], va[6], va[7]};
        const s16x4 v10 = {vb[0], vb[1], vb[2], vb[3]};
        const s16x4 v11 = {vb[4], vb[5], vb[6], vb[7]};
        #pragma unroll
        for (int ti = 0; ti < 2; ++ti) {
            const f32x4 s0 = __builtin_amdgcn_mfma_f32_16x16x32_bf16(ka, qf[ti], zf, 0, 0, 0);
            const f32x4 s1 = __builtin_amdgcn_mfma_f32_16x16x32_bf16(kb, qf[ti], zf, 0, 0, 0);
            const float p0 = __builtin_amdgcn_exp2f(s0[0] - MEXP_);
            const float p1 = __builtin_amdgcn_exp2f(s0[1] - MEXP_);
            const float p2 = __builtin_amdgcn_exp2f(s0[2] - MEXP_);
            const float p3 = __builtin_amdgcn_exp2f(s0[3] - MEXP_);
            const float p4 = __builtin_amdgcn_exp2f(s1[0] - MEXP_);
            const float p5 = __builtin_amdgcn_exp2f(s1[1] - MEXP_);
            const float p6 = __builtin_amdgcn_exp2f(s1[2] - MEXP_);
            const float p7 = __builtin_amdgcn_exp2f(s1[3] - MEXP_);
            ssum[ti] += ((p0 + p1) + (p2 + p3)) + ((p4 + p5) + (p6 + p7));
            const s16x4 pb0 = pack4(p0, p1, p2, p3);
            const s16x4 pb1 = pack4(p4, p5, p6, p7);
            o[ti][0] = __builtin_amdgcn_mfma_f32_16x16x16bf16_1k(v00, pb0, o[ti][0], 0, 0, 0);
            o[ti][0] = __builtin_amdgcn_mfma_f32_16x16x16bf16_1k(v01, pb1, o[ti][0], 0, 0, 0);
            o[ti][1] = __builtin_amdgcn_mfma_f32_16x16x16bf16_1k(v10, pb0, o[ti][1], 0, 0, 0);
            o[ti][1] = __builtin_amdgcn_mfma_f32_16x16x16bf16_1k(v11, pb1, o[ti][1], 0, 0, 0);
        }
    };

    // ---- fully unrolled chunk loops: static bases ----
    #pragma unroll
    for (int ch = 0; ch < 14; ++ch) compute(kwb + ch * 1024, vwb + ch * 1024);
    #pragma unroll
    for (int pc = 0; pc < 4; ++pc)  compute(kpb + pc * 1024, vpb + pc * 1024);

    // ---- epilogue: denom reduce, virtual zeros, LePE (RMW on out), store ----
    #pragma unroll
    for (int ti = 0; ti < 2; ++ti) {
        float den = ssum[ti];
        den += __shfl_xor(den, 16);
        den += __shfl_xor(den, 32);
        den += VIRT_ * 0.0000152587890625f; // 320 * 2^-16
        const float osc = 1.0f / den;       // for q = l15, valid in every lane

        const int qrow = (tbase + ti * 7) * 16 + l15;
        const int t = qrow / 224, rr = qrow % 224;
        const int h = rr >> 2, wi = rr & 3;
        const size_t off = (size_t)(b * T_ + t) * P1_ + h * WC_ + (ww * 4 + wi) * C_ + cbase;
        const f32x4 lp0 = *(const f32x4*)(out + off + g * 4);
        const f32x4 lp1 = *(const f32x4*)(out + off + 16 + g * 4);
        f32x4 val0, val1;
        #pragma unroll
        for (int r = 0; r < 4; ++r) {
            val0[r] = o[ti][0][r] * osc + lp0[r];
            val1[r] = o[ti][1][r] * osc + lp1[r];
        }
        *(f32x4*)(out + off + g * 4)      = val0;
        *(f32x4*)(out + off + 16 + g * 4) = val1;
    }
}

// ---------------------------------------------------------------------------
extern "C" void kernel_launch(void* const* d_in, const int* in_sizes, int n_in,
                              void* d_out, int out_size, void* d_ws, size_t ws_size,
                              hipStream_t stream) {
    const float* qkv = (const float*)d_in[0];
    const float* gw  = (const float*)d_in[1];
    const float* gb  = (const float*)d_in[2];
    const float* pw  = (const float*)d_in[3];
    const float* pb  = (const float*)d_in[4];

    const size_t plane = (size_t)B_ * T_ * H_ * W_ * C_; // 3,211,264
    const float* q_in = qkv;
    const float* k_in = qkv + plane;
    const float* v_in = qkv + 2 * plane;

    // ws: kw 6.42MB + vw 6.42MB + kp/vp 0.26MB + stripes 3.21MB = 16.3MB
    bf16* kw = (bf16*)d_ws;                        // plane bf16
    bf16* vw = kw + plane;                         // plane bf16
    bf16* kp = vw + plane;                         // 65,536 bf16
    bf16* vp = kp + (size_t)16 * NPOOL_ * 32;      // 65,536 bf16
    float* pmk_part = (float*)(vp + (size_t)16 * NPOOL_ * 32); // 7*57344 f32
    float* pmv_part = pmk_part + 7 * (size_t)PMSZ_;            // 7*57344 f32
    float* outp = (float*)d_out;

    hipLaunchKernelGGL(pre_kernel, dim3(392), dim3(256), 0, stream,
                       k_in, v_in, pw, gw, gb, kw, vw, outp, pmk_part, pmv_part);
    hipLaunchKernelGGL(finalize_kernel, dim3(16), dim3(256), 0, stream,
                       pmk_part, pmv_part, pb, kp, vp);
    hipLaunchKernelGGL(attn_kernel, dim3(448), dim3(448), 0, stream,
                       q_in, kw, vw, kp, vp, outp);
}